// Round 5
// baseline (936.319 us; speedup 1.0000x reference)
//
#include <hip/hip_runtime.h>

#define BB 64
#define LL 2048
#define TT 128

typedef float v4f __attribute__((ext_vector_type(4)));

__device__ __forceinline__ float rl(float v, int k) {
    return __uint_as_float(__builtin_amdgcn_readlane(__float_as_uint(v), k));
}

// ---------------- numerator: gold path score per batch ----------------
__global__ __launch_bounds__(256) void crf_num_kernel(
    const float* __restrict__ em, const int* __restrict__ tgt,
    const int* __restrict__ mask, const float* __restrict__ start,
    const float* __restrict__ endt, const float* __restrict__ trans,
    float* __restrict__ num_out)
{
    const int b = blockIdx.x;
    const int t = threadIdx.x;
    const int wave = t >> 6, lane = t & 63;
    const float* emb = em + (size_t)b * LL * TT;
    const int* tb = tgt + (size_t)b * LL;
    const int* mb = mask + (size_t)b * LL;

    float acc = 0.f;
    int msum = 0;
    for (int l = t; l < LL; l += 256) {
        int mv = mb[l];
        msum += mv;
        if (l >= 1 && mv > 0) {
            int tp = tb[l - 1], tc = tb[l];
            acc += trans[tp * TT + tc] + emb[(size_t)l * TT + tc];
        }
    }
    __shared__ float sacc[4];
    __shared__ int smsum[4];
    #pragma unroll
    for (int off = 32; off; off >>= 1) {
        acc += __shfl_xor(acc, off);
        msum += __shfl_xor(msum, off);
    }
    if (lane == 0) { sacc[wave] = acc; smsum[wave] = msum; }
    __syncthreads();
    if (t == 0) {
        float tot = sacc[0] + sacc[1] + sacc[2] + sacc[3];
        int total_mask = smsum[0] + smsum[1] + smsum[2] + smsum[3];
        int t0 = tb[0];
        tot += start[t0] + emb[t0];
        int se = total_mask - 1;
        int lt = tb[se];
        tot += endt[lt];
        num_out[b] = tot;
    }
}

// ---------------- denominator: forward algorithm, 1 block per batch ----------------
// Diagonal wave layout (4 waves):
//   wave w: owns s for jown = (w&1)*64+lane; computes partial for columns
//   jtgt = (w>>1)*64+lane using k-chunk = own j-range (kbase = (w&1)*64).
// => p[k] for the wave's k-chunk is ALWAYS in its own lanes: broadcast via
//    v_readlane (VALU pipe, per-SIMD) instead of LDS broadcast reads.
// Per step: exp -> 64x{readlane+fmac} -> ds_write partial -> ONE barrier ->
//           read 2 partials (double-buffered) -> add/log/masked-update.
// Offset m = s_{i-2}[0] via lag LDS slot (exactly inverted in update -> exact).
__global__ __launch_bounds__(256, 1) __attribute__((amdgpu_waves_per_eu(1, 2)))
void crf_forward_kernel(
    const float* __restrict__ em, const int* __restrict__ mask,
    const float* __restrict__ start, const float* __restrict__ endt,
    const float* __restrict__ trans, float* __restrict__ den_out)
{
    const int b = blockIdx.x;
    const int t = threadIdx.x;        // 0..255
    const int w = t >> 6;             // wave 0..3
    const int l = t & 63;             // lane
    const int jr   = w & 1;           // own j-range index
    const int tjr  = w >> 1;          // target j-range index
    const int jown = (jr  << 6) + l;  // own tag (s, em, start, end)
    const int jtgt = (tjr << 6) + l;  // target column (E, partial)
    const int kbase = jr << 6;        // k-chunk base (= own range)

    __shared__ float partial_sh[2][2][2][64];  // [buf][tjr][khalf][lane]
    __shared__ float s0_sh[2];                 // lag offset slots
    __shared__ int   mask_sh[LL];
    __shared__ float red[4], red2[4];

    const float* emb = em + (size_t)b * LL * TT;
    const int* mb = mask + (size_t)b * LL;

    for (int x = t; x < LL; x += 256) mask_sh[x] = mb[x];

    // cjE: normalizer for E block (target column); cjS: for own column update
    float cjE = -1e30f, cjS = -1e30f;
    for (int k = 0; k < TT; ++k) {
        cjE = fmaxf(cjE, trans[k * TT + jtgt]);
        cjS = fmaxf(cjS, trans[k * TT + jown]);
    }

#define EINIT(n) const v4f E##n = { \
    __expf(trans[(kbase + 4*(n) + 0) * TT + jtgt] - cjE), \
    __expf(trans[(kbase + 4*(n) + 1) * TT + jtgt] - cjE), \
    __expf(trans[(kbase + 4*(n) + 2) * TT + jtgt] - cjE), \
    __expf(trans[(kbase + 4*(n) + 3) * TT + jtgt] - cjE) };
    EINIT(0)  EINIT(1)  EINIT(2)  EINIT(3)
    EINIT(4)  EINIT(5)  EINIT(6)  EINIT(7)
    EINIT(8)  EINIT(9)  EINIT(10) EINIT(11)
    EINIT(12) EINIT(13) EINIT(14) EINIT(15)
#undef EINIT

    float s = start[jown] + emb[jown];
    if (t == 0) { s0_sh[0] = s; s0_sh[1] = s; }   // seed both lag slots with s_0[0]
    __syncthreads();                               // fences mask_sh + s0_sh
    float m_reg = s0_sh[0];                        // broadcast of s_0[0]

    // 4-deep rolling prefetch of emission values for OWN tag
    float emA = emb[(size_t)1 * TT + jown];
    float emB = emb[(size_t)2 * TT + jown];
    float emC = emb[(size_t)3 * TT + jown];
    float emD = emb[(size_t)4 * TT + jown];

    for (int i = 1; i < LL; ++i) {
        const float em_cur = emA;
        emA = emB; emB = emC; emC = emD;
        if (i + 4 < LL) emD = emb[(size_t)(i + 4) * TT + jown];

        const float p = __expf(s - m_reg);         // local: own tag's p

        // partial[jtgt] = sum_{k in own chunk} p[k] * E[k][jtgt]
        float a0 = 0.f, a1 = 0.f, a2 = 0.f, a3 = 0.f;
#define FMA4(n) \
        a0 = fmaf(rl(p, 4*(n)+0), E##n.x, a0); \
        a1 = fmaf(rl(p, 4*(n)+1), E##n.y, a1); \
        a2 = fmaf(rl(p, 4*(n)+2), E##n.z, a2); \
        a3 = fmaf(rl(p, 4*(n)+3), E##n.w, a3);
        FMA4(0)  FMA4(1)  FMA4(2)  FMA4(3)
        FMA4(4)  FMA4(5)  FMA4(6)  FMA4(7)
        FMA4(8)  FMA4(9)  FMA4(10) FMA4(11)
        FMA4(12) FMA4(13) FMA4(14) FMA4(15)
#undef FMA4
        const float partial = (a0 + a2) + (a1 + a3);

        const int buf = i & 1;
        partial_sh[buf][tjr][jr][l] = partial;     // jr == k-half index here
        if (t == 0) s0_sh[buf] = s;                // s_{i-1}[0] -> m for step i+1
        __syncthreads();                           // the ONLY barrier per step

        const float pa = partial_sh[buf][jr][0][l];
        const float pb = partial_sh[buf][jr][1][l];
        const float mnext = s0_sh[buf];
        const float acc = pa + pb;

        const float snew = em_cur + m_reg + cjS + __logf(acc);
        s = (mask_sh[i] > 0) ? snew : s;
        m_reg = mnext;
    }

    // den = logsumexp_j(s[j] + end[j]); waves 0,1 cover all tags, 2,3 duplicate
    float v = s + endt[jown];
    float m2 = v;
    #pragma unroll
    for (int off = 32; off; off >>= 1) m2 = fmaxf(m2, __shfl_xor(m2, off));
    if (l == 0) red2[w] = m2;
    __syncthreads();
    m2 = fmaxf(fmaxf(red2[0], red2[1]), fmaxf(red2[2], red2[3]));
    float e = (w < 2) ? __expf(v - m2) : 0.f;      // count each tag once
    #pragma unroll
    for (int off = 32; off; off >>= 1) e += __shfl_xor(e, off);
    if (l == 0) red[w] = e;
    __syncthreads();
    if (t == 0) den_out[b] = m2 + __logf(red[0] + red[1] + red[2] + red[3]);
}

// ---------------- final: out = sum_b (den_b - num_b) ----------------
__global__ void crf_final_kernel(const float* __restrict__ den,
                                 const float* __restrict__ num,
                                 float* __restrict__ out)
{
    int t = threadIdx.x;   // 64 threads == BB
    float v = den[t] - num[t];
    #pragma unroll
    for (int off = 32; off; off >>= 1) v += __shfl_xor(v, off);
    if (t == 0) out[0] = v;
}

extern "C" void kernel_launch(void* const* d_in, const int* in_sizes, int n_in,
                              void* d_out, int out_size, void* d_ws, size_t ws_size,
                              hipStream_t stream)
{
    const float* em    = (const float*)d_in[0];   // [B,L,T] f32
    const int*   tgt   = (const int*)d_in[1];     // [B,L]
    const int*   mask  = (const int*)d_in[2];     // [B,L]
    const float* start = (const float*)d_in[3];   // [T]
    const float* endt  = (const float*)d_in[4];   // [T]
    const float* trans = (const float*)d_in[5];   // [T,T]
    float* out = (float*)d_out;

    float* den = (float*)d_ws;        // BB floats
    float* num = den + BB;            // BB floats

    crf_num_kernel<<<BB, 256, 0, stream>>>(em, tgt, mask, start, endt, trans, num);
    crf_forward_kernel<<<BB, 256, 0, stream>>>(em, mask, start, endt, trans, den);
    crf_final_kernel<<<1, 64, 0, stream>>>(den, num, out);
}